// Round 1
// baseline (579.578 us; speedup 1.0000x reference)
//
#include <hip/hip_runtime.h>

#define BLOCK 256

// ---------- CSR build ----------

__global__ void hist_kernel(const int* __restrict__ nidx, int* __restrict__ counts, int E) {
    int i = blockIdx.x * blockDim.x + threadIdx.x;
    if (i < E) {
        int m = nidx[i];
        if (m >= 0) atomicAdd(&counts[m], 1);
    }
}

// per-block sum of a chunk of counts
__global__ void blocksum_kernel(const int* __restrict__ counts, int* __restrict__ bsum,
                                int N, int chunk) {
    __shared__ int sdata[BLOCK];
    int t = threadIdx.x;
    int base = blockIdx.x * chunk;
    int s = 0;
    for (int j = t; j < chunk; j += BLOCK) {
        int i = base + j;
        if (i < N) s += counts[i];
    }
    sdata[t] = s;
    __syncthreads();
    for (int d = BLOCK / 2; d > 0; d >>= 1) {
        if (t < d) sdata[t] += sdata[t + d];
        __syncthreads();
    }
    if (t == 0) bsum[blockIdx.x] = sdata[0];
}

// single block: exclusive scan of block sums (NB <= 512), in place.
// also writes row_start[N] = total.
__global__ void scanblocks_kernel(int* __restrict__ bsum, int* __restrict__ row_start_N, int NB) {
    __shared__ int s[512];
    int t = threadIdx.x;
    int v = (t < NB) ? bsum[t] : 0;
    s[t] = v;
    __syncthreads();
    for (int d = 1; d < 512; d <<= 1) {
        int x = (t >= d) ? s[t - d] : 0;
        __syncthreads();
        s[t] += x;
        __syncthreads();
    }
    if (t < NB) bsum[t] = (t == 0) ? 0 : s[t - 1];
    if (t == 0) *row_start_N = s[NB - 1];
}

// per-block exclusive scan of its chunk, offset by block offset -> row_start[0..N)
__global__ void scan_kernel(const int* __restrict__ counts, const int* __restrict__ bofs,
                            int* __restrict__ row_start, int N, int chunk) {
    __shared__ int sdata[BLOCK];
    int t = threadIdx.x;
    int items = chunk / BLOCK;            // <= 8
    int base = blockIdx.x * chunk + t * items;
    int local[8];
    int tsum = 0;
    for (int j = 0; j < items; ++j) {
        int i = base + j;
        int c = (i < N) ? counts[i] : 0;
        local[j] = tsum;                  // exclusive within thread
        tsum += c;
    }
    sdata[t] = tsum;
    __syncthreads();
    for (int d = 1; d < BLOCK; d <<= 1) {
        int x = (t >= d) ? sdata[t - d] : 0;
        __syncthreads();
        sdata[t] += x;
        __syncthreads();
    }
    int tpre = (t == 0) ? 0 : sdata[t - 1];
    int off = bofs[blockIdx.x] + tpre;
    for (int j = 0; j < items; ++j) {
        int i = base + j;
        if (i < N) row_start[i] = off + local[j];
    }
}

__global__ void fill_kernel(const int* __restrict__ nidx, const int* __restrict__ row_start,
                            int* __restrict__ cursor, int* __restrict__ edges, int E) {
    int i = blockIdx.x * blockDim.x + threadIdx.x;
    if (i < E) {
        int m = nidx[i];
        if (m >= 0) {
            int p = row_start[m] + atomicAdd(&cursor[m], 1);
            edges[p] = i;   // linear edge id: n*K + k
        }
    }
}

// ---------- gather + normalize ----------
// one wave (64 lanes) per output row; F=128 -> one float2 per lane.
__global__ void gather_kernel(const float* __restrict__ feat, const float* __restrict__ wdown,
                              const int* __restrict__ edges, const int* __restrict__ row_start,
                              const int* __restrict__ sel, float* __restrict__ out,
                              int n_up, int K) {
    int gid = blockIdx.x * blockDim.x + threadIdx.x;
    int u = gid >> 6;
    int lane = threadIdx.x & 63;
    if (u >= n_up) return;
    int m = sel[u];
    int p0 = row_start[m];
    int p1 = row_start[m + 1];
    const float2* f2 = (const float2*)feat;
    float2 acc = make_float2(0.f, 0.f);
    float ws = 0.f;
    for (int p = p0; p < p1; ++p) {
        int e = edges[p];        // same addr across wave -> broadcast
        float wt = wdown[e];
        int n = e / K;
        float2 f = f2[(size_t)n * 64 + lane];
        acc.x = fmaf(wt, f.x, acc.x);
        acc.y = fmaf(wt, f.y, acc.y);
        ws += wt;
    }
    // wsum = relu(ws); wsum = wsum > 0 ? wsum : 0.001; out = acc / wsum
    float d = (ws > 0.f) ? ws : 0.001f;
    float2 o;
    o.x = acc.x / d;
    o.y = acc.y / d;
    ((float2*)out)[(size_t)u * 64 + lane] = o;
}

extern "C" void kernel_launch(void* const* d_in, const int* in_sizes, int n_in,
                              void* d_out, int out_size, void* d_ws, size_t ws_size,
                              hipStream_t stream) {
    const float* features = (const float*)d_in[0];
    const float* wdown    = (const float*)d_in[1];
    const int*   nidx     = (const int*)d_in[2];
    const int*   sel      = (const int*)d_in[3];
    float* out = (float*)d_out;

    int E    = in_sizes[1];            // N*K = 2,000,000
    int n_up = in_sizes[3];            // 100,000
    int F    = out_size / n_up;        // 128
    int N    = in_sizes[0] / F;        // 400,000
    int K    = E / N;                  // 5

    // workspace layout (ints)
    int* counts    = (int*)d_ws;
    int* cursor    = counts + N;
    int* row_start = cursor + N;       // N+1 entries
    int* bsum      = row_start + (N + 1);
    int* edges     = bsum + 512;       // E entries

    int chunk = 1024;
    int NB = (N + chunk - 1) / chunk;
    while (NB > 512) { chunk *= 2; NB = (N + chunk - 1) / chunk; }

    hipMemsetAsync(counts, 0, sizeof(int) * (size_t)(2 * N), stream);   // counts + cursor

    hist_kernel<<<(E + BLOCK - 1) / BLOCK, BLOCK, 0, stream>>>(nidx, counts, E);
    blocksum_kernel<<<NB, BLOCK, 0, stream>>>(counts, bsum, N, chunk);
    scanblocks_kernel<<<1, 512, 0, stream>>>(bsum, row_start + N, NB);
    scan_kernel<<<NB, BLOCK, 0, stream>>>(counts, bsum, row_start, N, chunk);
    fill_kernel<<<(E + BLOCK - 1) / BLOCK, BLOCK, 0, stream>>>(nidx, row_start, cursor, edges, E);

    long long threads = (long long)n_up * 64;
    gather_kernel<<<(int)((threads + BLOCK - 1) / BLOCK), BLOCK, 0, stream>>>(
        features, wdown, edges, row_start, sel, out, n_up, K);
}

// Round 2
// 376.554 us; speedup vs baseline: 1.5392x; 1.5392x over previous
//
#include <hip/hip_runtime.h>

#define BLOCK 256

// ---------- selected-node marking ----------
__global__ void mark_kernel(const int* __restrict__ sel, unsigned char* __restrict__ flags, int n_up) {
    int u = blockIdx.x * blockDim.x + threadIdx.x;
    if (u < n_up) flags[sel[u]] = 1;
}

// ---------- histogram of in-edges into SELECTED nodes ----------
__global__ void hist_kernel(const int* __restrict__ nidx, const unsigned char* __restrict__ flags,
                            int* __restrict__ counts, int E) {
    int i4 = blockIdx.x * blockDim.x + threadIdx.x;
    int base = i4 * 4;
    if (base + 3 < E) {
        int4 mm = ((const int4*)nidx)[i4];
        int m;
        m = mm.x; if (m >= 0 && flags[m]) atomicAdd(&counts[m], 1);
        m = mm.y; if (m >= 0 && flags[m]) atomicAdd(&counts[m], 1);
        m = mm.z; if (m >= 0 && flags[m]) atomicAdd(&counts[m], 1);
        m = mm.w; if (m >= 0 && flags[m]) atomicAdd(&counts[m], 1);
    } else if (base < E) {
        for (int e = base; e < E; ++e) {
            int m = nidx[e];
            if (m >= 0 && flags[m]) atomicAdd(&counts[m], 1);
        }
    }
}

// per-block sum of a chunk of counts
__global__ void blocksum_kernel(const int* __restrict__ counts, int* __restrict__ bsum,
                                int N, int chunk) {
    __shared__ int sdata[BLOCK];
    int t = threadIdx.x;
    int base = blockIdx.x * chunk;
    int s = 0;
    for (int j = t; j < chunk; j += BLOCK) {
        int i = base + j;
        if (i < N) s += counts[i];
    }
    sdata[t] = s;
    __syncthreads();
    for (int d = BLOCK / 2; d > 0; d >>= 1) {
        if (t < d) sdata[t] += sdata[t + d];
        __syncthreads();
    }
    if (t == 0) bsum[blockIdx.x] = sdata[0];
}

// single block: exclusive scan of block sums (NB <= 512), in place; row_start[N]=total
__global__ void scanblocks_kernel(int* __restrict__ bsum, int* __restrict__ row_start_N, int NB) {
    __shared__ int s[512];
    int t = threadIdx.x;
    int v = (t < NB) ? bsum[t] : 0;
    s[t] = v;
    __syncthreads();
    for (int d = 1; d < 512; d <<= 1) {
        int x = (t >= d) ? s[t - d] : 0;
        __syncthreads();
        s[t] += x;
        __syncthreads();
    }
    if (t < NB) bsum[t] = (t == 0) ? 0 : s[t - 1];
    if (t == 0) *row_start_N = s[NB - 1];
}

// per-block exclusive scan of its chunk -> row_start AND cursor (init copy)
__global__ void scan_kernel(const int* __restrict__ counts, const int* __restrict__ bofs,
                            int* __restrict__ row_start, int* __restrict__ cursor,
                            int N, int chunk) {
    __shared__ int sdata[BLOCK];
    int t = threadIdx.x;
    int items = chunk / BLOCK;            // <= 8
    int base = blockIdx.x * chunk + t * items;
    int local[8];
    int tsum = 0;
    for (int j = 0; j < items; ++j) {
        int i = base + j;
        int c = (i < N) ? counts[i] : 0;
        local[j] = tsum;
        tsum += c;
    }
    sdata[t] = tsum;
    __syncthreads();
    for (int d = 1; d < BLOCK; d <<= 1) {
        int x = (t >= d) ? sdata[t - d] : 0;
        __syncthreads();
        sdata[t] += x;
        __syncthreads();
    }
    int tpre = (t == 0) ? 0 : sdata[t - 1];
    int off = bofs[blockIdx.x] + tpre;
    for (int j = 0; j < items; ++j) {
        int i = base + j;
        if (i < N) {
            int v = off + local[j];
            row_start[i] = v;
            cursor[i] = v;
        }
    }
}

// precompute per-output-row CSR range: rowinfo[u] = {p0, p1}
__global__ void selprep_kernel(const int* __restrict__ sel, const int* __restrict__ row_start,
                               int2* __restrict__ rowinfo, int n_up) {
    int u = blockIdx.x * blockDim.x + threadIdx.x;
    if (u < n_up) {
        int m = sel[u];
        rowinfo[u] = make_int2(row_start[m], row_start[m + 1]);
    }
}

// fill CSR with (src_node, weight_bits) pairs for selected destinations
__global__ void fill_kernel(const int* __restrict__ nidx, const float* __restrict__ wdown,
                            const unsigned char* __restrict__ flags,
                            int* __restrict__ cursor, int2* __restrict__ pairs, int E, int K) {
    int i4 = blockIdx.x * blockDim.x + threadIdx.x;
    int base = i4 * 4;
    if (base + 3 < E) {
        int4 mm = ((const int4*)nidx)[i4];
        float4 ww = ((const float4*)wdown)[i4];
        int m; int e;
        m = mm.x; if (m >= 0 && flags[m]) { e = base;     int p = atomicAdd(&cursor[m], 1); pairs[p] = make_int2(e / K, __float_as_int(ww.x)); }
        m = mm.y; if (m >= 0 && flags[m]) { e = base + 1; int p = atomicAdd(&cursor[m], 1); pairs[p] = make_int2(e / K, __float_as_int(ww.y)); }
        m = mm.z; if (m >= 0 && flags[m]) { e = base + 2; int p = atomicAdd(&cursor[m], 1); pairs[p] = make_int2(e / K, __float_as_int(ww.z)); }
        m = mm.w; if (m >= 0 && flags[m]) { e = base + 3; int p = atomicAdd(&cursor[m], 1); pairs[p] = make_int2(e / K, __float_as_int(ww.w)); }
    } else if (base < E) {
        for (int e = base; e < E; ++e) {
            int m = nidx[e];
            if (m >= 0 && flags[m]) {
                int p = atomicAdd(&cursor[m], 1);
                pairs[p] = make_int2(e / K, __float_as_int(wdown[e]));
            }
        }
    }
}

// ---------- gather + normalize ----------
// one wave per output row; F=128 -> one float2 per lane.
// lanes load CSR pairs in parallel, broadcast via shfl, feature loads issued 4 at a time.
__global__ void gather_kernel(const float* __restrict__ feat, const int2* __restrict__ pairs,
                              const int2* __restrict__ rowinfo, float* __restrict__ out,
                              int n_up) {
    int gid = blockIdx.x * blockDim.x + threadIdx.x;
    int u = gid >> 6;
    int lane = threadIdx.x & 63;
    if (u >= n_up) return;
    int2 ri = rowinfo[u];            // wave-uniform broadcast
    int p0 = ri.x;
    int deg = ri.y - ri.x;
    const float2* f2 = (const float2*)feat;
    float2 acc = make_float2(0.f, 0.f);
    float ws = 0.f;
    for (int b = 0; b < deg; b += 64) {
        int cnt = deg - b; if (cnt > 64) cnt = 64;
        int nsrc = 0; float wv = 0.f;
        if (lane < cnt) {
            int2 pr = pairs[p0 + b + lane];
            nsrc = pr.x;
            wv = __int_as_float(pr.y);
        }
        int j = 0;
        for (; j + 4 <= cnt; j += 4) {
            int n0 = __shfl(nsrc, j),     n1 = __shfl(nsrc, j + 1);
            int n2 = __shfl(nsrc, j + 2), n3 = __shfl(nsrc, j + 3);
            float w0 = __shfl(wv, j),     w1 = __shfl(wv, j + 1);
            float w2 = __shfl(wv, j + 2), w3 = __shfl(wv, j + 3);
            float2 f0 = f2[(size_t)n0 * 64 + lane];
            float2 f1 = f2[(size_t)n1 * 64 + lane];
            float2 fa = f2[(size_t)n2 * 64 + lane];
            float2 fb = f2[(size_t)n3 * 64 + lane];
            acc.x = fmaf(w0, f0.x, acc.x); acc.y = fmaf(w0, f0.y, acc.y);
            acc.x = fmaf(w1, f1.x, acc.x); acc.y = fmaf(w1, f1.y, acc.y);
            acc.x = fmaf(w2, fa.x, acc.x); acc.y = fmaf(w2, fa.y, acc.y);
            acc.x = fmaf(w3, fb.x, acc.x); acc.y = fmaf(w3, fb.y, acc.y);
            ws += w0 + w1 + w2 + w3;
        }
        for (; j < cnt; ++j) {
            int n0 = __shfl(nsrc, j);
            float w0 = __shfl(wv, j);
            float2 f0 = f2[(size_t)n0 * 64 + lane];
            acc.x = fmaf(w0, f0.x, acc.x);
            acc.y = fmaf(w0, f0.y, acc.y);
            ws += w0;
        }
    }
    float d = (ws > 0.f) ? ws : 0.001f;
    ((float2*)out)[(size_t)u * 64 + lane] = make_float2(acc.x / d, acc.y / d);
}

extern "C" void kernel_launch(void* const* d_in, const int* in_sizes, int n_in,
                              void* d_out, int out_size, void* d_ws, size_t ws_size,
                              hipStream_t stream) {
    const float* features = (const float*)d_in[0];
    const float* wdown    = (const float*)d_in[1];
    const int*   nidx     = (const int*)d_in[2];
    const int*   sel      = (const int*)d_in[3];
    float* out = (float*)d_out;

    int E    = in_sizes[1];            // N*K = 2,000,000
    int n_up = in_sizes[3];            // 100,000
    int F    = out_size / n_up;        // 128
    int N    = in_sizes[0] / F;        // 400,000
    int K    = E / N;                  // 5

    // workspace layout (int units). [counts N][flags N bytes][cursor N]
    // [row_start N+1][bsum 512][pad][rowinfo n_up int2][pairs E int2]
    int flags_ints = (N + 3) / 4;
    int* counts = (int*)d_ws;
    unsigned char* flags = (unsigned char*)(counts + N);
    int* cursor = counts + N + flags_ints;
    int* row_start = cursor + N;
    int* bsum = row_start + (N + 1);
    size_t off = (size_t)(N + flags_ints + N + (N + 1) + 512);
    off = (off + 1) & ~(size_t)1;          // 8B align
    int2* rowinfo = (int2*)((int*)d_ws + off);
    off += (size_t)2 * n_up;
    int2* pairs = (int2*)((int*)d_ws + off);

    int chunk = 1024;
    int NB = (N + chunk - 1) / chunk;
    while (NB > 512) { chunk *= 2; NB = (N + chunk - 1) / chunk; }

    // zero counts + flags in one shot
    hipMemsetAsync(counts, 0, (size_t)N * sizeof(int) + (size_t)flags_ints * sizeof(int), stream);

    mark_kernel<<<(n_up + BLOCK - 1) / BLOCK, BLOCK, 0, stream>>>(sel, flags, n_up);
    int e4 = (E + 3) / 4;
    hist_kernel<<<(e4 + BLOCK - 1) / BLOCK, BLOCK, 0, stream>>>(nidx, flags, counts, E);
    blocksum_kernel<<<NB, BLOCK, 0, stream>>>(counts, bsum, N, chunk);
    scanblocks_kernel<<<1, 512, 0, stream>>>(bsum, row_start + N, NB);
    scan_kernel<<<NB, BLOCK, 0, stream>>>(counts, bsum, row_start, cursor, N, chunk);
    selprep_kernel<<<(n_up + BLOCK - 1) / BLOCK, BLOCK, 0, stream>>>(sel, row_start, rowinfo, n_up);
    fill_kernel<<<(e4 + BLOCK - 1) / BLOCK, BLOCK, 0, stream>>>(nidx, wdown, flags, cursor, pairs, E, K);

    long long threads = (long long)n_up * 64;
    gather_kernel<<<(int)((threads + BLOCK - 1) / BLOCK), BLOCK, 0, stream>>>(
        features, pairs, rowinfo, out, n_up);
}